// Round 8
// baseline (494.028 us; speedup 1.0000x reference)
//
#include <hip/hip_runtime.h>

// ChebClassifier R8: interleaved [N0][6xfloat4] level-0 T records (2-line
// gathers in g18pool), 4x edge-unrolled props with batched pair loads,
// dead fp32 T5 writes dropped. Build/GEMM/head unchanged from R7.

namespace {
constexpr int cN0 = 100000, cN1 = 25000, cN2 = 6250;
constexpr int cE0 = 600000, cE1 = 150000, cE2 = 37500;
constexpr int cD  = cN2 * 256;

constexpr int JN[8]  = {cN0, cN1, cN2, cN1, cN2, cN0, cN1, cN2};
constexpr int JE[8]  = {cE0, cE1, cE2, 100000, 25000, cE0, cE1, cE2};
constexpr int JB[8]  = {391, 98, 25, 98, 25, 391, 98, 25};
constexpr int JBBASE[9] = {0, 391, 489, 514, 612, 637, 1028, 1126, 1151};
constexpr int TB = 1151;
constexpr int JCB[8] = {293, 74, 19, 49, 13, 293, 74, 19};
constexpr int JCBASE[9] = {0, 293, 367, 386, 435, 448, 741, 815, 834};
constexpr int TCB = 834;
constexpr int CHUNK = 2048;
constexpr int BSTRIDE = 400;

constexpr int EBASE[5]   = {0, 600000, 750000, 787500, 887500};
constexpr int E_TOTAL    = 912500;
constexpr int SBASE[3]   = {0, 600000, 750000};
constexpr int S_TOTAL    = 787500;
constexpr int NBASE[5]   = {0, 100096, 125184, 131584, 156672};
constexpr int NPAD_TOTAL = 163072;
constexpr int DEGBASE[3] = {0, 100000, 125000};
constexpr int DEG_TOTAL  = 131250;
}

typedef __attribute__((ext_vector_type(8))) short short8;
typedef __attribute__((ext_vector_type(4))) float floatx4;

__device__ inline ushort f2bf(float f) {
  union { float f; unsigned u; } v; v.f = f;
  unsigned u = v.u;
  return (ushort)((u + 0x7FFFu + ((u >> 16) & 1u)) >> 16);
}

__device__ inline int job_of_cb(int cb) {
  int j = 0;
  while (cb >= JCBASE[j + 1]) ++j;
  return j;
}
__device__ inline int job_of_bucket(int g) {
  int j = 0;
  while (g >= JBBASE[j + 1]) ++j;
  return j;
}

// ---------------- atomic-free CSR build (unchanged) ----------------
__global__ __launch_bounds__(256) void c1_count_kernel(
    const int* __restrict__ k0, const int* __restrict__ k1, const int* __restrict__ k2,
    const int* __restrict__ k3, const int* __restrict__ k4, const int* __restrict__ k5,
    const int* __restrict__ k6, const int* __restrict__ k7,
    int* __restrict__ cntCB) {
  __shared__ int cnt[BSTRIDE];
  int cb = blockIdx.x;
  int j = job_of_cb(cb);
  int lb = cb - JCBASE[j];
  const int* keys;
  switch (j) {
    case 0: keys = k0; break; case 1: keys = k1; break; case 2: keys = k2; break;
    case 3: keys = k3; break; case 4: keys = k4; break; case 5: keys = k5; break;
    case 6: keys = k6; break; default: keys = k7; break;
  }
  int nB = JB[j];
  for (int b = threadIdx.x; b < nB; b += 256) cnt[b] = 0;
  __syncthreads();
  int e0 = lb * CHUNK;
  int e1 = min(e0 + CHUNK, JE[j]);
  for (int e = e0 + threadIdx.x; e < e1; e += 256)
    atomicAdd(&cnt[keys[e] >> 8], 1);
  __syncthreads();
  for (int b = threadIdx.x; b < nB; b += 256)
    cntCB[cb * BSTRIDE + b] = cnt[b];
}

__global__ __launch_bounds__(256) void c2a_scan_kernel(int* __restrict__ cntCB,
                                                       int* __restrict__ bucketTot) {
  __shared__ int s[256];
  int g = blockIdx.x;
  int j = job_of_bucket(g);
  int b = g - JBBASE[j];
  int cb0 = JCBASE[j], nCB = JCB[j];
  int carry = 0;
  for (int c0 = 0; c0 < nCB; c0 += 256) {
    int i = c0 + threadIdx.x;
    int v = (i < nCB) ? cntCB[(cb0 + i) * BSTRIDE + b] : 0;
    s[threadIdx.x] = v;
    __syncthreads();
    for (int d = 1; d < 256; d <<= 1) {
      int t = (threadIdx.x >= d) ? s[threadIdx.x - d] : 0;
      __syncthreads();
      s[threadIdx.x] += t;
      __syncthreads();
    }
    if (i < nCB) cntCB[(cb0 + i) * BSTRIDE + b] = carry + s[threadIdx.x] - v;
    carry += s[255];
    __syncthreads();
  }
  if (threadIdx.x == 0) bucketTot[g] = carry;
}

__global__ __launch_bounds__(256) void c2b_scan_kernel(const int* __restrict__ bucketTot,
                                                       int* __restrict__ bucketBase) {
  __shared__ int s[256];
  int j = blockIdx.x;
  int g0 = JBBASE[j], nB = JB[j];
  int carry = 0;
  for (int c0 = 0; c0 < nB; c0 += 256) {
    int i = c0 + threadIdx.x;
    int v = (i < nB) ? bucketTot[g0 + i] : 0;
    s[threadIdx.x] = v;
    __syncthreads();
    for (int d = 1; d < 256; d <<= 1) {
      int t = (threadIdx.x >= d) ? s[threadIdx.x - d] : 0;
      __syncthreads();
      s[threadIdx.x] += t;
      __syncthreads();
    }
    if (i < nB) bucketBase[g0 + i] = carry + s[threadIdx.x] - v;
    carry += s[255];
    __syncthreads();
  }
}

__global__ __launch_bounds__(256) void c3_src_kernel(
    const int* __restrict__ s0, const int* __restrict__ s1, const int* __restrict__ s2,
    const int* __restrict__ cntCB, const int* __restrict__ bucketBase,
    int* __restrict__ scatSrc) {
  __shared__ int base[BSTRIDE];
  int cb = blockIdx.x + JCBASE[5];
  int j = job_of_cb(cb);
  int lb = cb - JCBASE[j];
  const int* keys = (j == 5) ? s0 : (j == 6) ? s1 : s2;
  int nB = JB[j];
  for (int b = threadIdx.x; b < nB; b += 256)
    base[b] = SBASE[j - 5] + bucketBase[JBBASE[j] + b] + cntCB[cb * BSTRIDE + b];
  __syncthreads();
  int e0 = lb * CHUNK;
  int e1 = min(e0 + CHUNK, JE[j]);
  for (int e = e0 + threadIdx.x; e < e1; e += 256) {
    int s = keys[e];
    int pos = atomicAdd(&base[s >> 8], 1);
    scatSrc[pos] = s & 255;
  }
}

__global__ __launch_bounds__(256) void ddeg_kernel(const int* __restrict__ scatSrc,
                                                   const int* __restrict__ bucketTot,
                                                   const int* __restrict__ bucketBase,
                                                   float* __restrict__ dinv) {
  __shared__ int cnt[256];
  int g = blockIdx.x + JBBASE[5];
  int j = job_of_bucket(g);
  int b = g - JBBASE[j];
  int st = SBASE[j - 5] + bucketBase[g];
  int en = st + bucketTot[g];
  cnt[threadIdx.x] = 0;
  __syncthreads();
  for (int idx = st + threadIdx.x; idx < en; idx += 256)
    atomicAdd(&cnt[scatSrc[idx]], 1);
  __syncthreads();
  int node = b * 256 + threadIdx.x;
  if (node < JN[j]) {
    int c = cnt[threadIdx.x];
    dinv[DEGBASE[j - 5] + node] = (c > 0) ? rsqrtf((float)c) : 0.f;
  }
}

__global__ __launch_bounds__(256) void c3_dst_kernel(
    const int* __restrict__ d0, const int* __restrict__ s0,
    const int* __restrict__ d1, const int* __restrict__ s1,
    const int* __restrict__ d2, const int* __restrict__ s2,
    const int* __restrict__ p0r, const int* __restrict__ p0c, const float* __restrict__ p0v,
    const int* __restrict__ p1r, const int* __restrict__ p1c, const float* __restrict__ p1v,
    const float* __restrict__ dinv,
    const int* __restrict__ cntCB, const int* __restrict__ bucketBase,
    int2* __restrict__ scatPairs) {
  __shared__ int base[BSTRIDE];
  int cb = blockIdx.x;
  int j = job_of_cb(cb);
  int lb = cb - JCBASE[j];
  const int* dk; const int* sk; const float* vv = nullptr;
  switch (j) {
    case 0: dk = d0; sk = s0; break;
    case 1: dk = d1; sk = s1; break;
    case 2: dk = d2; sk = s2; break;
    case 3: dk = p0r; sk = p0c; vv = p0v; break;
    default: dk = p1r; sk = p1c; vv = p1v; break;
  }
  int nB = JB[j];
  for (int b = threadIdx.x; b < nB; b += 256)
    base[b] = EBASE[j] + bucketBase[JBBASE[j] + b] + cntCB[cb * BSTRIDE + b];
  __syncthreads();
  int e0 = lb * CHUNK;
  int e1 = min(e0 + CHUNK, JE[j]);
  for (int e = e0 + threadIdx.x; e < e1; e += 256) {
    int d = dk[e];
    int s = sk[e];
    float w;
    if (j < 3) w = -(dinv[DEGBASE[j] + s] * dinv[DEGBASE[j] + d]);
    else w = vv[e];
    int pos = atomicAdd(&base[d >> 8], 1);
    scatPairs[pos] = make_int2(((d & 255) << 17) | s, __float_as_int(w));
  }
}

__global__ __launch_bounds__(256) void dcsr_kernel(const int2* __restrict__ scatPairs,
                                                   const int* __restrict__ bucketTot,
                                                   const int* __restrict__ bucketBase,
                                                   int* __restrict__ off,
                                                   int2* __restrict__ csrPairs) {
  __shared__ int cnt[256];
  __shared__ int sArr[256];
  __shared__ int cur[256];
  int g = blockIdx.x;
  int j = job_of_bucket(g);
  int b = g - JBBASE[j];
  int relBase = bucketBase[g];
  int st = EBASE[j] + relBase;
  int en = st + bucketTot[g];
  cnt[threadIdx.x] = 0;
  __syncthreads();
  for (int idx = st + threadIdx.x; idx < en; idx += 256)
    atomicAdd(&cnt[scatPairs[idx].x >> 17], 1);
  __syncthreads();
  int v = cnt[threadIdx.x];
  sArr[threadIdx.x] = v;
  __syncthreads();
  for (int d = 1; d < 256; d <<= 1) {
    int t = (threadIdx.x >= d) ? sArr[threadIdx.x - d] : 0;
    __syncthreads();
    sArr[threadIdx.x] += t;
    __syncthreads();
  }
  int excl = sArr[threadIdx.x] - v;
  int node = b * 256 + threadIdx.x;
  if (node < JN[j]) off[NBASE[j] + node] = relBase + excl;
  if (threadIdx.x == 0 && b == JB[j] - 1) off[NBASE[j] + JN[j]] = JE[j];
  cur[threadIdx.x] = st + excl;
  __syncthreads();
  for (int idx = st + threadIdx.x; idx < en; idx += 256) {
    int2 p = scatPairs[idx];
    int dl = p.x >> 17;
    int s = p.x & 0x1FFFF;
    int pos = atomicAdd(&cur[dl], 1);
    csrPairs[pos] = make_int2(s, p.y);
  }
}

// ---------------- props ----------------
// 32 lanes/row, float4, 4x edge unroll. fp32 y optional (null = skip), bf16 ybf.
__global__ __launch_bounds__(256) void csr_prop128_kernel(
    const int* __restrict__ off, const int2* __restrict__ pairs,
    const float* __restrict__ h, float* __restrict__ y, ushort* __restrict__ ybf,
    const float* __restrict__ prev, float scale, int N) {
  int r = blockIdx.x * 8 + (threadIdx.x >> 5);
  int l = threadIdx.x & 31;
  if (r >= N) return;
  int s = off[r], e = off[r + 1];
  const float4* h4 = (const float4*)h;
  float ax = 0.f, ay = 0.f, az = 0.f, aw = 0.f;
  int j = s;
  for (; j + 4 <= e; j += 4) {
    int2 p0 = pairs[j], p1 = pairs[j + 1], p2 = pairs[j + 2], p3 = pairs[j + 3];
    float4 v0 = h4[(size_t)p0.x * 32 + l];
    float4 v1 = h4[(size_t)p1.x * 32 + l];
    float4 v2 = h4[(size_t)p2.x * 32 + l];
    float4 v3 = h4[(size_t)p3.x * 32 + l];
    float w0 = __int_as_float(p0.y), w1 = __int_as_float(p1.y);
    float w2 = __int_as_float(p2.y), w3 = __int_as_float(p3.y);
    ax += w0 * v0.x + w1 * v1.x + w2 * v2.x + w3 * v3.x;
    ay += w0 * v0.y + w1 * v1.y + w2 * v2.y + w3 * v3.y;
    az += w0 * v0.z + w1 * v1.z + w2 * v2.z + w3 * v3.z;
    aw += w0 * v0.w + w1 * v1.w + w2 * v2.w + w3 * v3.w;
  }
  for (; j < e; ++j) {
    int2 p = pairs[j];
    float4 v0 = h4[(size_t)p.x * 32 + l];
    float w = __int_as_float(p.y);
    ax += w * v0.x; ay += w * v0.y; az += w * v0.z; aw += w * v0.w;
  }
  float4 v = make_float4(scale * ax, scale * ay, scale * az, scale * aw);
  if (prev) {
    float4 pv = ((const float4*)prev)[(size_t)r * 32 + l];
    v.x -= pv.x; v.y -= pv.y; v.z -= pv.z; v.w -= pv.w;
  }
  if (y) ((float4*)y)[(size_t)r * 32 + l] = v;
  uint2 sp = make_uint2(f2bf(v.x) | ((unsigned)f2bf(v.y) << 16),
                        f2bf(v.z) | ((unsigned)f2bf(v.w) << 16));
  ((uint2*)ybf)[(size_t)r * 32 + l] = sp;
}

// level-0: interleaved T records [N0][6] float4 (96 B/node)
__global__ void csr_prop3_kernel(const int* __restrict__ off, const int2* __restrict__ pairs,
                                 const float4* __restrict__ T, float4* __restrict__ Tout,
                                 int kin, int kout, int kprev, float scale, int N) {
  int r = blockIdx.x * blockDim.x + threadIdx.x;
  if (r >= N) return;
  int s = off[r], e = off[r + 1];
  float ax = 0.f, ay = 0.f, az = 0.f;
  int j = s;
  for (; j + 4 <= e; j += 4) {
    int2 p0 = pairs[j], p1 = pairs[j + 1], p2 = pairs[j + 2], p3 = pairs[j + 3];
    float4 h0 = T[(size_t)p0.x * 6 + kin];
    float4 h1 = T[(size_t)p1.x * 6 + kin];
    float4 h2 = T[(size_t)p2.x * 6 + kin];
    float4 h3 = T[(size_t)p3.x * 6 + kin];
    float w0 = __int_as_float(p0.y), w1 = __int_as_float(p1.y);
    float w2 = __int_as_float(p2.y), w3 = __int_as_float(p3.y);
    ax += w0 * h0.x + w1 * h1.x + w2 * h2.x + w3 * h3.x;
    ay += w0 * h0.y + w1 * h1.y + w2 * h2.y + w3 * h3.y;
    az += w0 * h0.z + w1 * h1.z + w2 * h2.z + w3 * h3.z;
  }
  for (; j < e; ++j) {
    int2 p = pairs[j];
    float4 hv = T[(size_t)p.x * 6 + kin];
    float w = __int_as_float(p.y);
    ax += w * hv.x; ay += w * hv.y; az += w * hv.z;
  }
  float4 v = make_float4(scale * ax, scale * ay, scale * az, 0.f);
  if (kprev >= 0) {
    float4 pv = T[(size_t)r * 6 + kprev];
    v.x -= pv.x; v.y -= pv.y; v.z -= pv.z;
  }
  Tout[(size_t)r * 6 + kout] = v;
}

__global__ void copyx_kernel(const float* __restrict__ x, float4* __restrict__ Tb, int N) {
  int r = blockIdx.x * 256 + threadIdx.x;
  if (r < N) Tb[(size_t)r * 6] = make_float4(x[3 * r], x[3 * r + 1], x[3 * r + 2], 0.f);
}

// fused gemm18 + pool0 over interleaved records, 2x edge unroll
__global__ __launch_bounds__(256) void g18pool_kernel(
    const int* __restrict__ off, const int2* __restrict__ pairs,
    const float4* __restrict__ Tb0, const float* __restrict__ W0,
    const float* __restrict__ b0, float* __restrict__ T0out,
    ushort* __restrict__ T0bf, int N) {
  int r = blockIdx.x * 2 + (threadIdx.x >> 7);
  int f = threadIdx.x & 127;
  float wcol[18];
#pragma unroll
  for (int t = 0; t < 18; ++t) wcol[t] = W0[t * 128 + f];
  float bv = b0[f];
  if (r >= N) return;
  int s = off[r], e = off[r + 1];
  float acc = 0.f;
  int j = s;
  for (; j + 2 <= e; j += 2) {
    int2 p0 = pairs[j], p1 = pairs[j + 1];
    const float4* t0 = Tb0 + (size_t)p0.x * 6;
    const float4* t1 = Tb0 + (size_t)p1.x * 6;
    float d0 = bv, d1 = bv;
#pragma unroll
    for (int k = 0; k < 6; ++k) {
      float4 a = t0[k];
      float4 b = t1[k];
      d0 += a.x * wcol[k * 3] + a.y * wcol[k * 3 + 1] + a.z * wcol[k * 3 + 2];
      d1 += b.x * wcol[k * 3] + b.y * wcol[k * 3 + 1] + b.z * wcol[k * 3 + 2];
    }
    acc += __int_as_float(p0.y) * fmaxf(d0, 0.f) + __int_as_float(p1.y) * fmaxf(d1, 0.f);
  }
  if (j < e) {
    int2 p = pairs[j];
    const float4* t0 = Tb0 + (size_t)p.x * 6;
    float d = bv;
#pragma unroll
    for (int k = 0; k < 6; ++k) {
      float4 a = t0[k];
      d += a.x * wcol[k * 3] + a.y * wcol[k * 3 + 1] + a.z * wcol[k * 3 + 2];
    }
    acc += __int_as_float(p.y) * fmaxf(d, 0.f);
  }
  T0out[(size_t)r * 128 + f] = acc;
  T0bf[(size_t)r * 128 + f] = f2bf(acc);
}

// ---------------- GEMM (bf16 A) ----------------
__global__ void prep_w_kernel(const float* __restrict__ W1, const float* __restrict__ W2,
                              ushort* __restrict__ Wt1, ushort* __restrict__ Wt2) {
  int i = blockIdx.x * 256 + threadIdx.x;
  if (i < 768 * 128) {
    int k = i / 128, n = i - k * 128;
    Wt1[(size_t)n * 768 + k] = f2bf(W1[i]);
  } else {
    int i2 = i - 768 * 128;
    if (i2 < 768 * 256) {
      int k = i2 / 256, n = i2 - k * 256;
      Wt2[(size_t)n * 768 + k] = f2bf(W2[i2]);
    }
  }
}

template <int RELU>
__global__ __launch_bounds__(256, 2) void gemm_mfma_kernel(
    const ushort* __restrict__ Tbf, const ushort* __restrict__ Wt,
    const float* __restrict__ bias, float* __restrict__ C, int M, int N) {
  __shared__ ushort Al[64][40];
  __shared__ ushort Bl[128][40];
  const int tid = threadIdx.x;
  const int rowBase = blockIdx.x * 64;
  const int colBase = blockIdx.y * 128;
  const int wave = tid >> 6;
  const int lane = tid & 63;
  const int m16 = lane & 15;
  const int quad = lane >> 4;
  const size_t Mstride = (size_t)M * 128;

  floatx4 acc[8];
#pragma unroll
  for (int c = 0; c < 8; ++c)
#pragma unroll
    for (int r = 0; r < 4; ++r) acc[c][r] = 0.f;

  const int sRow = tid >> 2;
  const int sK8 = (tid & 3) * 8;
  const int growA = rowBase + sRow;
  const bool aValid = growA < M;

  for (int kc = 0; kc < 24; ++kc) {
    uint4 av = make_uint4(0, 0, 0, 0);
    if (aValid)
      av = *(const uint4*)(Tbf + (size_t)(kc >> 2) * Mstride + (size_t)growA * 128
                           + ((kc & 3) << 5) + sK8);
    *(uint4*)&Al[sRow][sK8] = av;
#pragma unroll
    for (int l = 0; l < 2; ++l) {
      int lin = tid + l * 256;
      int bRow = lin >> 2;
      int bK8 = (lin & 3) * 8;
      *(uint4*)&Bl[bRow][bK8] =
          *(const uint4*)(Wt + (size_t)(colBase + bRow) * 768 + kc * 32 + bK8);
    }
    __syncthreads();

    short8 a = *(const short8*)&Al[wave * 16 + m16][quad * 8];
#pragma unroll
    for (int c = 0; c < 8; ++c) {
      short8 b = *(const short8*)&Bl[c * 16 + m16][quad * 8];
      acc[c] = __builtin_amdgcn_mfma_f32_16x16x32_bf16(a, b, acc[c], 0, 0, 0);
    }
    __syncthreads();
  }

#pragma unroll
  for (int c = 0; c < 8; ++c) {
    int col = colBase + c * 16 + m16;
    float bv = bias[col];
#pragma unroll
    for (int r = 0; r < 4; ++r) {
      int row = rowBase + wave * 16 + quad * 4 + r;
      if (row < M) {
        float v = acc[c][r] + bv;
        if (RELU) v = fmaxf(v, 0.f);
        C[(size_t)row * N + col] = v;
      }
    }
  }
}

// ---------------- linear head ----------------
__global__ void initout_kernel(float* __restrict__ out, const float* __restrict__ linb) {
  int i = threadIdx.x;
  if (i < 10) out[i] = linb[i];
}

__global__ __launch_bounds__(256) void linear_kernel(const float* __restrict__ Wl,
                                                     const float* __restrict__ h,
                                                     float* __restrict__ out, int D) {
  float p[10];
#pragma unroll
  for (int j = 0; j < 10; ++j) p[j] = 0.f;
  int stride = gridDim.x * blockDim.x;
  for (int i = blockIdx.x * blockDim.x + threadIdx.x; i < D; i += stride) {
    float hv = h[i];
#pragma unroll
    for (int j = 0; j < 10; ++j) p[j] += Wl[(size_t)j * D + i] * hv;
  }
#pragma unroll
  for (int j = 0; j < 10; ++j) {
#pragma unroll
    for (int off = 32; off > 0; off >>= 1) p[j] += __shfl_down(p[j], off, 64);
  }
  __shared__ float s[4][10];
  int wave = threadIdx.x >> 6, lane = threadIdx.x & 63;
  if (lane == 0) {
#pragma unroll
    for (int j = 0; j < 10; ++j) s[wave][j] = p[j];
  }
  __syncthreads();
  if (threadIdx.x < 10) {
    float t = s[0][threadIdx.x] + s[1][threadIdx.x] + s[2][threadIdx.x] + s[3][threadIdx.x];
    atomicAdd(&out[threadIdx.x], t);
  }
}

// ---------------- host orchestration ----------------
extern "C" void kernel_launch(void* const* d_in, const int* in_sizes, int n_in,
                              void* d_out, int out_size, void* d_ws, size_t ws_size,
                              hipStream_t stream) {
  const float* x    = (const float*)d_in[0];
  const int*   ei0  = (const int*)d_in[1];
  const int*   ei1  = (const int*)d_in[2];
  const int*   ei2  = (const int*)d_in[3];
  const float* W0   = (const float*)d_in[4];
  const float* b0   = (const float*)d_in[5];
  const float* W1   = (const float*)d_in[6];
  const float* b1   = (const float*)d_in[7];
  const float* W2   = (const float*)d_in[8];
  const float* b2   = (const float*)d_in[9];
  const int*   D0r  = (const int*)d_in[10];
  const int*   D0c  = (const int*)d_in[11];
  const float* D0v  = (const float*)d_in[12];
  const int*   D1r  = (const int*)d_in[13];
  const int*   D1c  = (const int*)d_in[14];
  const float* D1v  = (const float*)d_in[15];
  const float* linW = (const float*)d_in[16];
  const float* linb = (const float*)d_in[17];
  float* out = (float*)d_out;
  (void)in_sizes; (void)n_in; (void)out_size; (void)ws_size;

  const int* src0 = ei0;            const int* dst0 = ei0 + cE0;
  const int* src1 = ei1;            const int* dst1 = ei1 + cE1;
  const int* src2 = ei2;            const int* dst2 = ei2 + cE2;

  float* ws = (float*)d_ws;
  size_t off = 0;
  auto alloc = [&](size_t n) {
    float* p = ws + off;
    off += (n + 63) & ~size_t(63);
    return p;
  };
  float* dinv       = alloc(DEG_TOTAL);
  int*   cntCB      = (int*)alloc((size_t)TCB * BSTRIDE);
  int*   bucketTot  = (int*)alloc(TB);
  int*   bucketBase = (int*)alloc(TB);
  int*   scatSrc    = (int*)alloc(S_TOTAL);
  int2*  scatPairs  = (int2*)alloc((size_t)2 * E_TOTAL);
  int2*  csrPairs   = (int2*)alloc((size_t)2 * E_TOTAL);
  int*   offArr     = (int*)alloc(NPAD_TOTAL);
  ushort* Wt1       = (ushort*)alloc(768 * 128 / 2);
  ushort* Wt2       = (ushort*)alloc(768 * 256 / 2);
  float4* Tb0       = (float4*)alloc((size_t)cN0 * 24);  // [N0][6] float4
  float* Tlvl1      = alloc((size_t)6 * cN1 * 128);
  ushort* Tbf1      = (ushort*)alloc((size_t)6 * cN1 * 64);
  float* out1       = alloc((size_t)cN1 * 128);
  float* Tlvl2      = alloc((size_t)6 * cN2 * 128);
  ushort* Tbf2      = (ushort*)alloc((size_t)6 * cN2 * 64);
  float* out2       = alloc((size_t)cN2 * 256);

  auto nb = [](long long n) { return (unsigned)((n + 255) / 256); };

  // ---- atomic-free CSR build ----
  c1_count_kernel<<<TCB, 256, 0, stream>>>(dst0, dst1, dst2, D0r, D1r,
                                           src0, src1, src2, cntCB);
  c2a_scan_kernel<<<TB, 256, 0, stream>>>(cntCB, bucketTot);
  c2b_scan_kernel<<<8, 256, 0, stream>>>(bucketTot, bucketBase);
  c3_src_kernel<<<TCB - JCBASE[5], 256, 0, stream>>>(src0, src1, src2,
                                                     cntCB, bucketBase, scatSrc);
  ddeg_kernel<<<TB - JBBASE[5], 256, 0, stream>>>(scatSrc, bucketTot, bucketBase, dinv);
  c3_dst_kernel<<<JCBASE[5], 256, 0, stream>>>(dst0, src0, dst1, src1, dst2, src2,
                                               D0r, D0c, D0v, D1r, D1c, D1v,
                                               dinv, cntCB, bucketBase, scatPairs);
  dcsr_kernel<<<JBBASE[5], 256, 0, stream>>>(scatPairs, bucketTot, bucketBase,
                                             offArr, csrPairs);
  prep_w_kernel<<<nb(768 * 384), 256, 0, stream>>>(W1, W2, Wt1, Wt2);

  auto seg_off   = [&](int s) { return offArr + NBASE[s]; };
  auto seg_pairs = [&](int s) { return csrPairs + EBASE[s]; };

  // ================= Level 0 (F=3 -> 128, fused with pool0) =================
  copyx_kernel<<<nb(cN0), 256, 0, stream>>>(x, Tb0, cN0);
  csr_prop3_kernel<<<nb(cN0), 256, 0, stream>>>(seg_off(0), seg_pairs(0),
      Tb0, Tb0, 0, 1, -1, 1.f, cN0);
  csr_prop3_kernel<<<nb(cN0), 256, 0, stream>>>(seg_off(0), seg_pairs(0),
      Tb0, Tb0, 1, 2, 0, 2.f, cN0);
  csr_prop3_kernel<<<nb(cN0), 256, 0, stream>>>(seg_off(0), seg_pairs(0),
      Tb0, Tb0, 2, 3, 1, 2.f, cN0);
  csr_prop3_kernel<<<nb(cN0), 256, 0, stream>>>(seg_off(0), seg_pairs(0),
      Tb0, Tb0, 3, 4, 2, 2.f, cN0);
  csr_prop3_kernel<<<nb(cN0), 256, 0, stream>>>(seg_off(0), seg_pairs(0),
      Tb0, Tb0, 4, 5, 3, 2.f, cN0);
  g18pool_kernel<<<(cN1 + 1) / 2, 256, 0, stream>>>(
      seg_off(3), seg_pairs(3), Tb0, W0, b0, Tlvl1, Tbf1, cN1);

  // ================= Level 1 =================
  {
    auto Tk  = [&](int k) { return Tlvl1 + (size_t)k * cN1 * 128; };
    auto Tbk = [&](int k) { return Tbf1 + (size_t)k * cN1 * 128; };
    auto prop = [&](int kin, int kout, int kprev, float scale, bool needF32) {
      csr_prop128_kernel<<<(cN1 + 7) / 8, 256, 0, stream>>>(
          seg_off(1), seg_pairs(1), Tk(kin), needF32 ? Tk(kout) : nullptr, Tbk(kout),
          (kprev >= 0) ? Tk(kprev) : nullptr, scale, cN1);
    };
    prop(0, 1, -1, 1.f, true);
    prop(1, 2, 0, 2.f, true);
    prop(2, 3, 1, 2.f, true);
    prop(3, 4, 2, 2.f, true);
    prop(4, 5, 3, 2.f, false);   // T5 fp32 never read
    dim3 g((cN1 + 63) / 64, 1);
    gemm_mfma_kernel<1><<<g, 256, 0, stream>>>(Tbf1, Wt1, b1, out1, cN1, 128);
  }

  // pool1: out1 -> Tlvl2 block 0
  csr_prop128_kernel<<<(cN2 + 7) / 8, 256, 0, stream>>>(
      seg_off(4), seg_pairs(4), out1, Tlvl2, Tbf2, nullptr, 1.f, cN2);

  // ================= Level 2 (no relu, N=256) =================
  {
    auto Tk  = [&](int k) { return Tlvl2 + (size_t)k * cN2 * 128; };
    auto Tbk = [&](int k) { return Tbf2 + (size_t)k * cN2 * 128; };
    auto prop = [&](int kin, int kout, int kprev, float scale, bool needF32) {
      csr_prop128_kernel<<<(cN2 + 7) / 8, 256, 0, stream>>>(
          seg_off(2), seg_pairs(2), Tk(kin), needF32 ? Tk(kout) : nullptr, Tbk(kout),
          (kprev >= 0) ? Tk(kprev) : nullptr, scale, cN2);
    };
    prop(0, 1, -1, 1.f, true);
    prop(1, 2, 0, 2.f, true);
    prop(2, 3, 1, 2.f, true);
    prop(3, 4, 2, 2.f, true);
    prop(4, 5, 3, 2.f, false);   // T5 fp32 never read
    dim3 g((cN2 + 63) / 64, 2);
    gemm_mfma_kernel<0><<<g, 256, 0, stream>>>(Tbf2, Wt2, b2, out2, cN2, 256);
  }

  // ---- linear head ----
  initout_kernel<<<1, 64, 0, stream>>>(out, linb);
  linear_kernel<<<512, 256, 0, stream>>>(linW, out2, out, cD);
}

// Round 9
// 481.235 us; speedup vs baseline: 1.0266x; 1.0266x over previous
//
#include <hip/hip_runtime.h>

// ChebClassifier R9: R7 slab layout restored (coalesced prop3), fused
// g18pool split into dense h0_kernel (parallel, no gathers) + csr_prop128
// pool gather. R8's 4x-unroll props kept. Build/GEMM/head unchanged.

namespace {
constexpr int cN0 = 100000, cN1 = 25000, cN2 = 6250;
constexpr int cE0 = 600000, cE1 = 150000, cE2 = 37500;
constexpr int cD  = cN2 * 256;

constexpr int JN[8]  = {cN0, cN1, cN2, cN1, cN2, cN0, cN1, cN2};
constexpr int JE[8]  = {cE0, cE1, cE2, 100000, 25000, cE0, cE1, cE2};
constexpr int JB[8]  = {391, 98, 25, 98, 25, 391, 98, 25};
constexpr int JBBASE[9] = {0, 391, 489, 514, 612, 637, 1028, 1126, 1151};
constexpr int TB = 1151;
constexpr int JCB[8] = {293, 74, 19, 49, 13, 293, 74, 19};
constexpr int JCBASE[9] = {0, 293, 367, 386, 435, 448, 741, 815, 834};
constexpr int TCB = 834;
constexpr int CHUNK = 2048;
constexpr int BSTRIDE = 400;

constexpr int EBASE[5]   = {0, 600000, 750000, 787500, 887500};
constexpr int E_TOTAL    = 912500;
constexpr int SBASE[3]   = {0, 600000, 750000};
constexpr int S_TOTAL    = 787500;
constexpr int NBASE[5]   = {0, 100096, 125184, 131584, 156672};
constexpr int NPAD_TOTAL = 163072;
constexpr int DEGBASE[3] = {0, 100000, 125000};
constexpr int DEG_TOTAL  = 131250;
}

typedef __attribute__((ext_vector_type(8))) short short8;
typedef __attribute__((ext_vector_type(4))) float floatx4;

__device__ inline ushort f2bf(float f) {
  union { float f; unsigned u; } v; v.f = f;
  unsigned u = v.u;
  return (ushort)((u + 0x7FFFu + ((u >> 16) & 1u)) >> 16);
}

__device__ inline int job_of_cb(int cb) {
  int j = 0;
  while (cb >= JCBASE[j + 1]) ++j;
  return j;
}
__device__ inline int job_of_bucket(int g) {
  int j = 0;
  while (g >= JBBASE[j + 1]) ++j;
  return j;
}

// ---------------- atomic-free CSR build (unchanged) ----------------
__global__ __launch_bounds__(256) void c1_count_kernel(
    const int* __restrict__ k0, const int* __restrict__ k1, const int* __restrict__ k2,
    const int* __restrict__ k3, const int* __restrict__ k4, const int* __restrict__ k5,
    const int* __restrict__ k6, const int* __restrict__ k7,
    int* __restrict__ cntCB) {
  __shared__ int cnt[BSTRIDE];
  int cb = blockIdx.x;
  int j = job_of_cb(cb);
  int lb = cb - JCBASE[j];
  const int* keys;
  switch (j) {
    case 0: keys = k0; break; case 1: keys = k1; break; case 2: keys = k2; break;
    case 3: keys = k3; break; case 4: keys = k4; break; case 5: keys = k5; break;
    case 6: keys = k6; break; default: keys = k7; break;
  }
  int nB = JB[j];
  for (int b = threadIdx.x; b < nB; b += 256) cnt[b] = 0;
  __syncthreads();
  int e0 = lb * CHUNK;
  int e1 = min(e0 + CHUNK, JE[j]);
  for (int e = e0 + threadIdx.x; e < e1; e += 256)
    atomicAdd(&cnt[keys[e] >> 8], 1);
  __syncthreads();
  for (int b = threadIdx.x; b < nB; b += 256)
    cntCB[cb * BSTRIDE + b] = cnt[b];
}

__global__ __launch_bounds__(256) void c2a_scan_kernel(int* __restrict__ cntCB,
                                                       int* __restrict__ bucketTot) {
  __shared__ int s[256];
  int g = blockIdx.x;
  int j = job_of_bucket(g);
  int b = g - JBBASE[j];
  int cb0 = JCBASE[j], nCB = JCB[j];
  int carry = 0;
  for (int c0 = 0; c0 < nCB; c0 += 256) {
    int i = c0 + threadIdx.x;
    int v = (i < nCB) ? cntCB[(cb0 + i) * BSTRIDE + b] : 0;
    s[threadIdx.x] = v;
    __syncthreads();
    for (int d = 1; d < 256; d <<= 1) {
      int t = (threadIdx.x >= d) ? s[threadIdx.x - d] : 0;
      __syncthreads();
      s[threadIdx.x] += t;
      __syncthreads();
    }
    if (i < nCB) cntCB[(cb0 + i) * BSTRIDE + b] = carry + s[threadIdx.x] - v;
    carry += s[255];
    __syncthreads();
  }
  if (threadIdx.x == 0) bucketTot[g] = carry;
}

__global__ __launch_bounds__(256) void c2b_scan_kernel(const int* __restrict__ bucketTot,
                                                       int* __restrict__ bucketBase) {
  __shared__ int s[256];
  int j = blockIdx.x;
  int g0 = JBBASE[j], nB = JB[j];
  int carry = 0;
  for (int c0 = 0; c0 < nB; c0 += 256) {
    int i = c0 + threadIdx.x;
    int v = (i < nB) ? bucketTot[g0 + i] : 0;
    s[threadIdx.x] = v;
    __syncthreads();
    for (int d = 1; d < 256; d <<= 1) {
      int t = (threadIdx.x >= d) ? s[threadIdx.x - d] : 0;
      __syncthreads();
      s[threadIdx.x] += t;
      __syncthreads();
    }
    if (i < nB) bucketBase[g0 + i] = carry + s[threadIdx.x] - v;
    carry += s[255];
    __syncthreads();
  }
}

__global__ __launch_bounds__(256) void c3_src_kernel(
    const int* __restrict__ s0, const int* __restrict__ s1, const int* __restrict__ s2,
    const int* __restrict__ cntCB, const int* __restrict__ bucketBase,
    int* __restrict__ scatSrc) {
  __shared__ int base[BSTRIDE];
  int cb = blockIdx.x + JCBASE[5];
  int j = job_of_cb(cb);
  int lb = cb - JCBASE[j];
  const int* keys = (j == 5) ? s0 : (j == 6) ? s1 : s2;
  int nB = JB[j];
  for (int b = threadIdx.x; b < nB; b += 256)
    base[b] = SBASE[j - 5] + bucketBase[JBBASE[j] + b] + cntCB[cb * BSTRIDE + b];
  __syncthreads();
  int e0 = lb * CHUNK;
  int e1 = min(e0 + CHUNK, JE[j]);
  for (int e = e0 + threadIdx.x; e < e1; e += 256) {
    int s = keys[e];
    int pos = atomicAdd(&base[s >> 8], 1);
    scatSrc[pos] = s & 255;
  }
}

__global__ __launch_bounds__(256) void ddeg_kernel(const int* __restrict__ scatSrc,
                                                   const int* __restrict__ bucketTot,
                                                   const int* __restrict__ bucketBase,
                                                   float* __restrict__ dinv) {
  __shared__ int cnt[256];
  int g = blockIdx.x + JBBASE[5];
  int j = job_of_bucket(g);
  int b = g - JBBASE[j];
  int st = SBASE[j - 5] + bucketBase[g];
  int en = st + bucketTot[g];
  cnt[threadIdx.x] = 0;
  __syncthreads();
  for (int idx = st + threadIdx.x; idx < en; idx += 256)
    atomicAdd(&cnt[scatSrc[idx]], 1);
  __syncthreads();
  int node = b * 256 + threadIdx.x;
  if (node < JN[j]) {
    int c = cnt[threadIdx.x];
    dinv[DEGBASE[j - 5] + node] = (c > 0) ? rsqrtf((float)c) : 0.f;
  }
}

__global__ __launch_bounds__(256) void c3_dst_kernel(
    const int* __restrict__ d0, const int* __restrict__ s0,
    const int* __restrict__ d1, const int* __restrict__ s1,
    const int* __restrict__ d2, const int* __restrict__ s2,
    const int* __restrict__ p0r, const int* __restrict__ p0c, const float* __restrict__ p0v,
    const int* __restrict__ p1r, const int* __restrict__ p1c, const float* __restrict__ p1v,
    const float* __restrict__ dinv,
    const int* __restrict__ cntCB, const int* __restrict__ bucketBase,
    int2* __restrict__ scatPairs) {
  __shared__ int base[BSTRIDE];
  int cb = blockIdx.x;
  int j = job_of_cb(cb);
  int lb = cb - JCBASE[j];
  const int* dk; const int* sk; const float* vv = nullptr;
  switch (j) {
    case 0: dk = d0; sk = s0; break;
    case 1: dk = d1; sk = s1; break;
    case 2: dk = d2; sk = s2; break;
    case 3: dk = p0r; sk = p0c; vv = p0v; break;
    default: dk = p1r; sk = p1c; vv = p1v; break;
  }
  int nB = JB[j];
  for (int b = threadIdx.x; b < nB; b += 256)
    base[b] = EBASE[j] + bucketBase[JBBASE[j] + b] + cntCB[cb * BSTRIDE + b];
  __syncthreads();
  int e0 = lb * CHUNK;
  int e1 = min(e0 + CHUNK, JE[j]);
  for (int e = e0 + threadIdx.x; e < e1; e += 256) {
    int d = dk[e];
    int s = sk[e];
    float w;
    if (j < 3) w = -(dinv[DEGBASE[j] + s] * dinv[DEGBASE[j] + d]);
    else w = vv[e];
    int pos = atomicAdd(&base[d >> 8], 1);
    scatPairs[pos] = make_int2(((d & 255) << 17) | s, __float_as_int(w));
  }
}

__global__ __launch_bounds__(256) void dcsr_kernel(const int2* __restrict__ scatPairs,
                                                   const int* __restrict__ bucketTot,
                                                   const int* __restrict__ bucketBase,
                                                   int* __restrict__ off,
                                                   int2* __restrict__ csrPairs) {
  __shared__ int cnt[256];
  __shared__ int sArr[256];
  __shared__ int cur[256];
  int g = blockIdx.x;
  int j = job_of_bucket(g);
  int b = g - JBBASE[j];
  int relBase = bucketBase[g];
  int st = EBASE[j] + relBase;
  int en = st + bucketTot[g];
  cnt[threadIdx.x] = 0;
  __syncthreads();
  for (int idx = st + threadIdx.x; idx < en; idx += 256)
    atomicAdd(&cnt[scatPairs[idx].x >> 17], 1);
  __syncthreads();
  int v = cnt[threadIdx.x];
  sArr[threadIdx.x] = v;
  __syncthreads();
  for (int d = 1; d < 256; d <<= 1) {
    int t = (threadIdx.x >= d) ? sArr[threadIdx.x - d] : 0;
    __syncthreads();
    sArr[threadIdx.x] += t;
    __syncthreads();
  }
  int excl = sArr[threadIdx.x] - v;
  int node = b * 256 + threadIdx.x;
  if (node < JN[j]) off[NBASE[j] + node] = relBase + excl;
  if (threadIdx.x == 0 && b == JB[j] - 1) off[NBASE[j] + JN[j]] = JE[j];
  cur[threadIdx.x] = st + excl;
  __syncthreads();
  for (int idx = st + threadIdx.x; idx < en; idx += 256) {
    int2 p = scatPairs[idx];
    int dl = p.x >> 17;
    int s = p.x & 0x1FFFF;
    int pos = atomicAdd(&cur[dl], 1);
    csrPairs[pos] = make_int2(s, p.y);
  }
}

// ---------------- props ----------------
// 32 lanes/row, float4, 4x edge unroll. fp32 y optional, bf16 ybf.
__global__ __launch_bounds__(256) void csr_prop128_kernel(
    const int* __restrict__ off, const int2* __restrict__ pairs,
    const float* __restrict__ h, float* __restrict__ y, ushort* __restrict__ ybf,
    const float* __restrict__ prev, float scale, int N) {
  int r = blockIdx.x * 8 + (threadIdx.x >> 5);
  int l = threadIdx.x & 31;
  if (r >= N) return;
  int s = off[r], e = off[r + 1];
  const float4* h4 = (const float4*)h;
  float ax = 0.f, ay = 0.f, az = 0.f, aw = 0.f;
  int j = s;
  for (; j + 4 <= e; j += 4) {
    int2 p0 = pairs[j], p1 = pairs[j + 1], p2 = pairs[j + 2], p3 = pairs[j + 3];
    float4 v0 = h4[(size_t)p0.x * 32 + l];
    float4 v1 = h4[(size_t)p1.x * 32 + l];
    float4 v2 = h4[(size_t)p2.x * 32 + l];
    float4 v3 = h4[(size_t)p3.x * 32 + l];
    float w0 = __int_as_float(p0.y), w1 = __int_as_float(p1.y);
    float w2 = __int_as_float(p2.y), w3 = __int_as_float(p3.y);
    ax += w0 * v0.x + w1 * v1.x + w2 * v2.x + w3 * v3.x;
    ay += w0 * v0.y + w1 * v1.y + w2 * v2.y + w3 * v3.y;
    az += w0 * v0.z + w1 * v1.z + w2 * v2.z + w3 * v3.z;
    aw += w0 * v0.w + w1 * v1.w + w2 * v2.w + w3 * v3.w;
  }
  for (; j < e; ++j) {
    int2 p = pairs[j];
    float4 v0 = h4[(size_t)p.x * 32 + l];
    float w = __int_as_float(p.y);
    ax += w * v0.x; ay += w * v0.y; az += w * v0.z; aw += w * v0.w;
  }
  float4 v = make_float4(scale * ax, scale * ay, scale * az, scale * aw);
  if (prev) {
    float4 pv = ((const float4*)prev)[(size_t)r * 32 + l];
    v.x -= pv.x; v.y -= pv.y; v.z -= pv.z; v.w -= pv.w;
  }
  if (y) ((float4*)y)[(size_t)r * 32 + l] = v;
  uint2 sp = make_uint2(f2bf(v.x) | ((unsigned)f2bf(v.y) << 16),
                        f2bf(v.z) | ((unsigned)f2bf(v.w) << 16));
  ((uint2*)ybf)[(size_t)r * 32 + l] = sp;
}

// level-0: slab layout, separate [N0] float4 arrays per T_k (R7 style)
__global__ void csr_prop3_kernel(const int* __restrict__ off, const int2* __restrict__ pairs,
                                 const float4* __restrict__ h, float4* __restrict__ y,
                                 const float4* __restrict__ prev, float scale, int N) {
  int r = blockIdx.x * blockDim.x + threadIdx.x;
  if (r >= N) return;
  int s = off[r], e = off[r + 1];
  float ax = 0.f, ay = 0.f, az = 0.f;
  int j = s;
  for (; j + 4 <= e; j += 4) {
    int2 p0 = pairs[j], p1 = pairs[j + 1], p2 = pairs[j + 2], p3 = pairs[j + 3];
    float4 h0 = h[p0.x], h1 = h[p1.x], h2 = h[p2.x], h3 = h[p3.x];
    float w0 = __int_as_float(p0.y), w1 = __int_as_float(p1.y);
    float w2 = __int_as_float(p2.y), w3 = __int_as_float(p3.y);
    ax += w0 * h0.x + w1 * h1.x + w2 * h2.x + w3 * h3.x;
    ay += w0 * h0.y + w1 * h1.y + w2 * h2.y + w3 * h3.y;
    az += w0 * h0.z + w1 * h1.z + w2 * h2.z + w3 * h3.z;
  }
  for (; j < e; ++j) {
    int2 p = pairs[j];
    float4 hv = h[p.x];
    float w = __int_as_float(p.y);
    ax += w * hv.x; ay += w * hv.y; az += w * hv.z;
  }
  float4 v = make_float4(scale * ax, scale * ay, scale * az, 0.f);
  if (prev) {
    float4 pv = prev[r];
    v.x -= pv.x; v.y -= pv.y; v.z -= pv.z;
  }
  y[r] = v;
}

__global__ void copyx_kernel(const float* __restrict__ x, float4* __restrict__ Tb, int N) {
  int r = blockIdx.x * 256 + threadIdx.x;
  if (r < N) Tb[r] = make_float4(x[3 * r], x[3 * r + 1], x[3 * r + 2], 0.f);
}

// dense h0 = relu(b0 + T18 . W0): 128 threads per row, no gathers
__global__ __launch_bounds__(256) void h0_kernel(
    const float4* __restrict__ Tb0, const float* __restrict__ W0,
    const float* __restrict__ b0, float* __restrict__ h0, int N0) {
  int r = blockIdx.x * 2 + (threadIdx.x >> 7);
  int f = threadIdx.x & 127;
  float wcol[18];
#pragma unroll
  for (int t = 0; t < 18; ++t) wcol[t] = W0[t * 128 + f];
  if (r >= N0) return;
  float d = b0[f];
#pragma unroll
  for (int k = 0; k < 6; ++k) {
    float4 t = Tb0[(size_t)k * N0 + r];
    d += t.x * wcol[k * 3] + t.y * wcol[k * 3 + 1] + t.z * wcol[k * 3 + 2];
  }
  h0[(size_t)r * 128 + f] = fmaxf(d, 0.f);
}

// ---------------- GEMM (bf16 A) ----------------
__global__ void prep_w_kernel(const float* __restrict__ W1, const float* __restrict__ W2,
                              ushort* __restrict__ Wt1, ushort* __restrict__ Wt2) {
  int i = blockIdx.x * 256 + threadIdx.x;
  if (i < 768 * 128) {
    int k = i / 128, n = i - k * 128;
    Wt1[(size_t)n * 768 + k] = f2bf(W1[i]);
  } else {
    int i2 = i - 768 * 128;
    if (i2 < 768 * 256) {
      int k = i2 / 256, n = i2 - k * 256;
      Wt2[(size_t)n * 768 + k] = f2bf(W2[i2]);
    }
  }
}

template <int RELU>
__global__ __launch_bounds__(256, 2) void gemm_mfma_kernel(
    const ushort* __restrict__ Tbf, const ushort* __restrict__ Wt,
    const float* __restrict__ bias, float* __restrict__ C, int M, int N) {
  __shared__ ushort Al[64][40];
  __shared__ ushort Bl[128][40];
  const int tid = threadIdx.x;
  const int rowBase = blockIdx.x * 64;
  const int colBase = blockIdx.y * 128;
  const int wave = tid >> 6;
  const int lane = tid & 63;
  const int m16 = lane & 15;
  const int quad = lane >> 4;
  const size_t Mstride = (size_t)M * 128;

  floatx4 acc[8];
#pragma unroll
  for (int c = 0; c < 8; ++c)
#pragma unroll
    for (int r = 0; r < 4; ++r) acc[c][r] = 0.f;

  const int sRow = tid >> 2;
  const int sK8 = (tid & 3) * 8;
  const int growA = rowBase + sRow;
  const bool aValid = growA < M;

  for (int kc = 0; kc < 24; ++kc) {
    uint4 av = make_uint4(0, 0, 0, 0);
    if (aValid)
      av = *(const uint4*)(Tbf + (size_t)(kc >> 2) * Mstride + (size_t)growA * 128
                           + ((kc & 3) << 5) + sK8);
    *(uint4*)&Al[sRow][sK8] = av;
#pragma unroll
    for (int l = 0; l < 2; ++l) {
      int lin = tid + l * 256;
      int bRow = lin >> 2;
      int bK8 = (lin & 3) * 8;
      *(uint4*)&Bl[bRow][bK8] =
          *(const uint4*)(Wt + (size_t)(colBase + bRow) * 768 + kc * 32 + bK8);
    }
    __syncthreads();

    short8 a = *(const short8*)&Al[wave * 16 + m16][quad * 8];
#pragma unroll
    for (int c = 0; c < 8; ++c) {
      short8 b = *(const short8*)&Bl[c * 16 + m16][quad * 8];
      acc[c] = __builtin_amdgcn_mfma_f32_16x16x32_bf16(a, b, acc[c], 0, 0, 0);
    }
    __syncthreads();
  }

#pragma unroll
  for (int c = 0; c < 8; ++c) {
    int col = colBase + c * 16 + m16;
    float bv = bias[col];
#pragma unroll
    for (int r = 0; r < 4; ++r) {
      int row = rowBase + wave * 16 + quad * 4 + r;
      if (row < M) {
        float v = acc[c][r] + bv;
        if (RELU) v = fmaxf(v, 0.f);
        C[(size_t)row * N + col] = v;
      }
    }
  }
}

// ---------------- linear head ----------------
__global__ void initout_kernel(float* __restrict__ out, const float* __restrict__ linb) {
  int i = threadIdx.x;
  if (i < 10) out[i] = linb[i];
}

__global__ __launch_bounds__(256) void linear_kernel(const float* __restrict__ Wl,
                                                     const float* __restrict__ h,
                                                     float* __restrict__ out, int D) {
  float p[10];
#pragma unroll
  for (int j = 0; j < 10; ++j) p[j] = 0.f;
  int stride = gridDim.x * blockDim.x;
  for (int i = blockIdx.x * blockDim.x + threadIdx.x; i < D; i += stride) {
    float hv = h[i];
#pragma unroll
    for (int j = 0; j < 10; ++j) p[j] += Wl[(size_t)j * D + i] * hv;
  }
#pragma unroll
  for (int j = 0; j < 10; ++j) {
#pragma unroll
    for (int off = 32; off > 0; off >>= 1) p[j] += __shfl_down(p[j], off, 64);
  }
  __shared__ float s[4][10];
  int wave = threadIdx.x >> 6, lane = threadIdx.x & 63;
  if (lane == 0) {
#pragma unroll
    for (int j = 0; j < 10; ++j) s[wave][j] = p[j];
  }
  __syncthreads();
  if (threadIdx.x < 10) {
    float t = s[0][threadIdx.x] + s[1][threadIdx.x] + s[2][threadIdx.x] + s[3][threadIdx.x];
    atomicAdd(&out[threadIdx.x], t);
  }
}

// ---------------- host orchestration ----------------
extern "C" void kernel_launch(void* const* d_in, const int* in_sizes, int n_in,
                              void* d_out, int out_size, void* d_ws, size_t ws_size,
                              hipStream_t stream) {
  const float* x    = (const float*)d_in[0];
  const int*   ei0  = (const int*)d_in[1];
  const int*   ei1  = (const int*)d_in[2];
  const int*   ei2  = (const int*)d_in[3];
  const float* W0   = (const float*)d_in[4];
  const float* b0   = (const float*)d_in[5];
  const float* W1   = (const float*)d_in[6];
  const float* b1   = (const float*)d_in[7];
  const float* W2   = (const float*)d_in[8];
  const float* b2   = (const float*)d_in[9];
  const int*   D0r  = (const int*)d_in[10];
  const int*   D0c  = (const int*)d_in[11];
  const float* D0v  = (const float*)d_in[12];
  const int*   D1r  = (const int*)d_in[13];
  const int*   D1c  = (const int*)d_in[14];
  const float* D1v  = (const float*)d_in[15];
  const float* linW = (const float*)d_in[16];
  const float* linb = (const float*)d_in[17];
  float* out = (float*)d_out;
  (void)in_sizes; (void)n_in; (void)out_size; (void)ws_size;

  const int* src0 = ei0;            const int* dst0 = ei0 + cE0;
  const int* src1 = ei1;            const int* dst1 = ei1 + cE1;
  const int* src2 = ei2;            const int* dst2 = ei2 + cE2;

  float* ws = (float*)d_ws;
  size_t off = 0;
  auto alloc = [&](size_t n) {
    float* p = ws + off;
    off += (n + 63) & ~size_t(63);
    return p;
  };
  float* dinv       = alloc(DEG_TOTAL);
  int*   cntCB      = (int*)alloc((size_t)TCB * BSTRIDE);
  int*   bucketTot  = (int*)alloc(TB);
  int*   bucketBase = (int*)alloc(TB);
  int*   scatSrc    = (int*)alloc(S_TOTAL);
  int2*  scatPairs  = (int2*)alloc((size_t)2 * E_TOTAL);
  int2*  csrPairs   = (int2*)alloc((size_t)2 * E_TOTAL);
  int*   offArr     = (int*)alloc(NPAD_TOTAL);
  ushort* Wt1       = (ushort*)alloc(768 * 128 / 2);
  ushort* Wt2       = (ushort*)alloc(768 * 256 / 2);
  float4* Tb0       = (float4*)alloc((size_t)6 * cN0 * 4);  // 6 slabs [N0] float4
  float* h0buf      = alloc((size_t)cN0 * 128);
  float* Tlvl1      = alloc((size_t)6 * cN1 * 128);
  ushort* Tbf1      = (ushort*)alloc((size_t)6 * cN1 * 64);
  float* out1       = alloc((size_t)cN1 * 128);
  float* Tlvl2      = alloc((size_t)6 * cN2 * 128);
  ushort* Tbf2      = (ushort*)alloc((size_t)6 * cN2 * 64);
  float* out2       = alloc((size_t)cN2 * 256);

  auto nb = [](long long n) { return (unsigned)((n + 255) / 256); };

  // ---- atomic-free CSR build ----
  c1_count_kernel<<<TCB, 256, 0, stream>>>(dst0, dst1, dst2, D0r, D1r,
                                           src0, src1, src2, cntCB);
  c2a_scan_kernel<<<TB, 256, 0, stream>>>(cntCB, bucketTot);
  c2b_scan_kernel<<<8, 256, 0, stream>>>(bucketTot, bucketBase);
  c3_src_kernel<<<TCB - JCBASE[5], 256, 0, stream>>>(src0, src1, src2,
                                                     cntCB, bucketBase, scatSrc);
  ddeg_kernel<<<TB - JBBASE[5], 256, 0, stream>>>(scatSrc, bucketTot, bucketBase, dinv);
  c3_dst_kernel<<<JCBASE[5], 256, 0, stream>>>(dst0, src0, dst1, src1, dst2, src2,
                                               D0r, D0c, D0v, D1r, D1c, D1v,
                                               dinv, cntCB, bucketBase, scatPairs);
  dcsr_kernel<<<JBBASE[5], 256, 0, stream>>>(scatPairs, bucketTot, bucketBase,
                                             offArr, csrPairs);
  prep_w_kernel<<<nb(768 * 384), 256, 0, stream>>>(W1, W2, Wt1, Wt2);

  auto seg_off   = [&](int s) { return offArr + NBASE[s]; };
  auto seg_pairs = [&](int s) { return csrPairs + EBASE[s]; };

  // ================= Level 0 (F=3 -> 128) =================
  copyx_kernel<<<nb(cN0), 256, 0, stream>>>(x, Tb0, cN0);
  {
    auto Tk = [&](int k) { return Tb0 + (size_t)k * cN0; };
    csr_prop3_kernel<<<nb(cN0), 256, 0, stream>>>(seg_off(0), seg_pairs(0),
        Tk(0), Tk(1), nullptr, 1.f, cN0);
    csr_prop3_kernel<<<nb(cN0), 256, 0, stream>>>(seg_off(0), seg_pairs(0),
        Tk(1), Tk(2), Tk(0), 2.f, cN0);
    csr_prop3_kernel<<<nb(cN0), 256, 0, stream>>>(seg_off(0), seg_pairs(0),
        Tk(2), Tk(3), Tk(1), 2.f, cN0);
    csr_prop3_kernel<<<nb(cN0), 256, 0, stream>>>(seg_off(0), seg_pairs(0),
        Tk(3), Tk(4), Tk(2), 2.f, cN0);
    csr_prop3_kernel<<<nb(cN0), 256, 0, stream>>>(seg_off(0), seg_pairs(0),
        Tk(4), Tk(5), Tk(3), 2.f, cN0);
  }
  // dense h0, then pool0 gather -> Tlvl1 block 0 (fp32 + bf16)
  h0_kernel<<<(cN0 + 1) / 2, 256, 0, stream>>>(Tb0, W0, b0, h0buf, cN0);
  csr_prop128_kernel<<<(cN1 + 7) / 8, 256, 0, stream>>>(
      seg_off(3), seg_pairs(3), h0buf, Tlvl1, Tbf1, nullptr, 1.f, cN1);

  // ================= Level 1 =================
  {
    auto Tk  = [&](int k) { return Tlvl1 + (size_t)k * cN1 * 128; };
    auto Tbk = [&](int k) { return Tbf1 + (size_t)k * cN1 * 128; };
    auto prop = [&](int kin, int kout, int kprev, float scale, bool needF32) {
      csr_prop128_kernel<<<(cN1 + 7) / 8, 256, 0, stream>>>(
          seg_off(1), seg_pairs(1), Tk(kin), needF32 ? Tk(kout) : nullptr, Tbk(kout),
          (kprev >= 0) ? Tk(kprev) : nullptr, scale, cN1);
    };
    prop(0, 1, -1, 1.f, true);
    prop(1, 2, 0, 2.f, true);
    prop(2, 3, 1, 2.f, true);
    prop(3, 4, 2, 2.f, true);
    prop(4, 5, 3, 2.f, false);   // T5 fp32 never read
    dim3 g((cN1 + 63) / 64, 1);
    gemm_mfma_kernel<1><<<g, 256, 0, stream>>>(Tbf1, Wt1, b1, out1, cN1, 128);
  }

  // pool1: out1 -> Tlvl2 block 0
  csr_prop128_kernel<<<(cN2 + 7) / 8, 256, 0, stream>>>(
      seg_off(4), seg_pairs(4), out1, Tlvl2, Tbf2, nullptr, 1.f, cN2);

  // ================= Level 2 (no relu, N=256) =================
  {
    auto Tk  = [&](int k) { return Tlvl2 + (size_t)k * cN2 * 128; };
    auto Tbk = [&](int k) { return Tbf2 + (size_t)k * cN2 * 128; };
    auto prop = [&](int kin, int kout, int kprev, float scale, bool needF32) {
      csr_prop128_kernel<<<(cN2 + 7) / 8, 256, 0, stream>>>(
          seg_off(2), seg_pairs(2), Tk(kin), needF32 ? Tk(kout) : nullptr, Tbk(kout),
          (kprev >= 0) ? Tk(kprev) : nullptr, scale, cN2);
    };
    prop(0, 1, -1, 1.f, true);
    prop(1, 2, 0, 2.f, true);
    prop(2, 3, 1, 2.f, true);
    prop(3, 4, 2, 2.f, true);
    prop(4, 5, 3, 2.f, false);   // T5 fp32 never read
    dim3 g((cN2 + 63) / 64, 2);
    gemm_mfma_kernel<0><<<g, 256, 0, stream>>>(Tbf2, Wt2, b2, out2, cN2, 256);
  }

  // ---- linear head ----
  initout_kernel<<<1, 64, 0, stream>>>(out, linb);
  linear_kernel<<<512, 256, 0, stream>>>(linW, out2, out, cD);
}

// Round 10
// 433.714 us; speedup vs baseline: 1.1391x; 1.1096x over previous
//
#include <hip/hip_runtime.h>

// ChebClassifier R10: h0 via single-K-chunk bf16 MFMA (A = [N0][32] bf16
// shadow written by copyx/prop3; W0b = [128][32] bf16). Replaces the
// VMEM-issue-bound h0_kernel (26 VMEM insts/output -> ~0.1). Rest = R9.

namespace {
constexpr int cN0 = 100000, cN1 = 25000, cN2 = 6250;
constexpr int cE0 = 600000, cE1 = 150000, cE2 = 37500;
constexpr int cD  = cN2 * 256;

constexpr int JN[8]  = {cN0, cN1, cN2, cN1, cN2, cN0, cN1, cN2};
constexpr int JE[8]  = {cE0, cE1, cE2, 100000, 25000, cE0, cE1, cE2};
constexpr int JB[8]  = {391, 98, 25, 98, 25, 391, 98, 25};
constexpr int JBBASE[9] = {0, 391, 489, 514, 612, 637, 1028, 1126, 1151};
constexpr int TB = 1151;
constexpr int JCB[8] = {293, 74, 19, 49, 13, 293, 74, 19};
constexpr int JCBASE[9] = {0, 293, 367, 386, 435, 448, 741, 815, 834};
constexpr int TCB = 834;
constexpr int CHUNK = 2048;
constexpr int BSTRIDE = 400;

constexpr int EBASE[5]   = {0, 600000, 750000, 787500, 887500};
constexpr int E_TOTAL    = 912500;
constexpr int SBASE[3]   = {0, 600000, 750000};
constexpr int S_TOTAL    = 787500;
constexpr int NBASE[5]   = {0, 100096, 125184, 131584, 156672};
constexpr int NPAD_TOTAL = 163072;
constexpr int DEGBASE[3] = {0, 100000, 125000};
constexpr int DEG_TOTAL  = 131250;
}

typedef __attribute__((ext_vector_type(8))) short short8;
typedef __attribute__((ext_vector_type(4))) float floatx4;

__device__ inline ushort f2bf(float f) {
  union { float f; unsigned u; } v; v.f = f;
  unsigned u = v.u;
  return (ushort)((u + 0x7FFFu + ((u >> 16) & 1u)) >> 16);
}

__device__ inline int job_of_cb(int cb) {
  int j = 0;
  while (cb >= JCBASE[j + 1]) ++j;
  return j;
}
__device__ inline int job_of_bucket(int g) {
  int j = 0;
  while (g >= JBBASE[j + 1]) ++j;
  return j;
}

// ---------------- atomic-free CSR build (unchanged) ----------------
__global__ __launch_bounds__(256) void c1_count_kernel(
    const int* __restrict__ k0, const int* __restrict__ k1, const int* __restrict__ k2,
    const int* __restrict__ k3, const int* __restrict__ k4, const int* __restrict__ k5,
    const int* __restrict__ k6, const int* __restrict__ k7,
    int* __restrict__ cntCB) {
  __shared__ int cnt[BSTRIDE];
  int cb = blockIdx.x;
  int j = job_of_cb(cb);
  int lb = cb - JCBASE[j];
  const int* keys;
  switch (j) {
    case 0: keys = k0; break; case 1: keys = k1; break; case 2: keys = k2; break;
    case 3: keys = k3; break; case 4: keys = k4; break; case 5: keys = k5; break;
    case 6: keys = k6; break; default: keys = k7; break;
  }
  int nB = JB[j];
  for (int b = threadIdx.x; b < nB; b += 256) cnt[b] = 0;
  __syncthreads();
  int e0 = lb * CHUNK;
  int e1 = min(e0 + CHUNK, JE[j]);
  for (int e = e0 + threadIdx.x; e < e1; e += 256)
    atomicAdd(&cnt[keys[e] >> 8], 1);
  __syncthreads();
  for (int b = threadIdx.x; b < nB; b += 256)
    cntCB[cb * BSTRIDE + b] = cnt[b];
}

__global__ __launch_bounds__(256) void c2a_scan_kernel(int* __restrict__ cntCB,
                                                       int* __restrict__ bucketTot) {
  __shared__ int s[256];
  int g = blockIdx.x;
  int j = job_of_bucket(g);
  int b = g - JBBASE[j];
  int cb0 = JCBASE[j], nCB = JCB[j];
  int carry = 0;
  for (int c0 = 0; c0 < nCB; c0 += 256) {
    int i = c0 + threadIdx.x;
    int v = (i < nCB) ? cntCB[(cb0 + i) * BSTRIDE + b] : 0;
    s[threadIdx.x] = v;
    __syncthreads();
    for (int d = 1; d < 256; d <<= 1) {
      int t = (threadIdx.x >= d) ? s[threadIdx.x - d] : 0;
      __syncthreads();
      s[threadIdx.x] += t;
      __syncthreads();
    }
    if (i < nCB) cntCB[(cb0 + i) * BSTRIDE + b] = carry + s[threadIdx.x] - v;
    carry += s[255];
    __syncthreads();
  }
  if (threadIdx.x == 0) bucketTot[g] = carry;
}

__global__ __launch_bounds__(256) void c2b_scan_kernel(const int* __restrict__ bucketTot,
                                                       int* __restrict__ bucketBase) {
  __shared__ int s[256];
  int j = blockIdx.x;
  int g0 = JBBASE[j], nB = JB[j];
  int carry = 0;
  for (int c0 = 0; c0 < nB; c0 += 256) {
    int i = c0 + threadIdx.x;
    int v = (i < nB) ? bucketTot[g0 + i] : 0;
    s[threadIdx.x] = v;
    __syncthreads();
    for (int d = 1; d < 256; d <<= 1) {
      int t = (threadIdx.x >= d) ? s[threadIdx.x - d] : 0;
      __syncthreads();
      s[threadIdx.x] += t;
      __syncthreads();
    }
    if (i < nB) bucketBase[g0 + i] = carry + s[threadIdx.x] - v;
    carry += s[255];
    __syncthreads();
  }
}

__global__ __launch_bounds__(256) void c3_src_kernel(
    const int* __restrict__ s0, const int* __restrict__ s1, const int* __restrict__ s2,
    const int* __restrict__ cntCB, const int* __restrict__ bucketBase,
    int* __restrict__ scatSrc) {
  __shared__ int base[BSTRIDE];
  int cb = blockIdx.x + JCBASE[5];
  int j = job_of_cb(cb);
  int lb = cb - JCBASE[j];
  const int* keys = (j == 5) ? s0 : (j == 6) ? s1 : s2;
  int nB = JB[j];
  for (int b = threadIdx.x; b < nB; b += 256)
    base[b] = SBASE[j - 5] + bucketBase[JBBASE[j] + b] + cntCB[cb * BSTRIDE + b];
  __syncthreads();
  int e0 = lb * CHUNK;
  int e1 = min(e0 + CHUNK, JE[j]);
  for (int e = e0 + threadIdx.x; e < e1; e += 256) {
    int s = keys[e];
    int pos = atomicAdd(&base[s >> 8], 1);
    scatSrc[pos] = s & 255;
  }
}

__global__ __launch_bounds__(256) void ddeg_kernel(const int* __restrict__ scatSrc,
                                                   const int* __restrict__ bucketTot,
                                                   const int* __restrict__ bucketBase,
                                                   float* __restrict__ dinv) {
  __shared__ int cnt[256];
  int g = blockIdx.x + JBBASE[5];
  int j = job_of_bucket(g);
  int b = g - JBBASE[j];
  int st = SBASE[j - 5] + bucketBase[g];
  int en = st + bucketTot[g];
  cnt[threadIdx.x] = 0;
  __syncthreads();
  for (int idx = st + threadIdx.x; idx < en; idx += 256)
    atomicAdd(&cnt[scatSrc[idx]], 1);
  __syncthreads();
  int node = b * 256 + threadIdx.x;
  if (node < JN[j]) {
    int c = cnt[threadIdx.x];
    dinv[DEGBASE[j - 5] + node] = (c > 0) ? rsqrtf((float)c) : 0.f;
  }
}

__global__ __launch_bounds__(256) void c3_dst_kernel(
    const int* __restrict__ d0, const int* __restrict__ s0,
    const int* __restrict__ d1, const int* __restrict__ s1,
    const int* __restrict__ d2, const int* __restrict__ s2,
    const int* __restrict__ p0r, const int* __restrict__ p0c, const float* __restrict__ p0v,
    const int* __restrict__ p1r, const int* __restrict__ p1c, const float* __restrict__ p1v,
    const float* __restrict__ dinv,
    const int* __restrict__ cntCB, const int* __restrict__ bucketBase,
    int2* __restrict__ scatPairs) {
  __shared__ int base[BSTRIDE];
  int cb = blockIdx.x;
  int j = job_of_cb(cb);
  int lb = cb - JCBASE[j];
  const int* dk; const int* sk; const float* vv = nullptr;
  switch (j) {
    case 0: dk = d0; sk = s0; break;
    case 1: dk = d1; sk = s1; break;
    case 2: dk = d2; sk = s2; break;
    case 3: dk = p0r; sk = p0c; vv = p0v; break;
    default: dk = p1r; sk = p1c; vv = p1v; break;
  }
  int nB = JB[j];
  for (int b = threadIdx.x; b < nB; b += 256)
    base[b] = EBASE[j] + bucketBase[JBBASE[j] + b] + cntCB[cb * BSTRIDE + b];
  __syncthreads();
  int e0 = lb * CHUNK;
  int e1 = min(e0 + CHUNK, JE[j]);
  for (int e = e0 + threadIdx.x; e < e1; e += 256) {
    int d = dk[e];
    int s = sk[e];
    float w;
    if (j < 3) w = -(dinv[DEGBASE[j] + s] * dinv[DEGBASE[j] + d]);
    else w = vv[e];
    int pos = atomicAdd(&base[d >> 8], 1);
    scatPairs[pos] = make_int2(((d & 255) << 17) | s, __float_as_int(w));
  }
}

__global__ __launch_bounds__(256) void dcsr_kernel(const int2* __restrict__ scatPairs,
                                                   const int* __restrict__ bucketTot,
                                                   const int* __restrict__ bucketBase,
                                                   int* __restrict__ off,
                                                   int2* __restrict__ csrPairs) {
  __shared__ int cnt[256];
  __shared__ int sArr[256];
  __shared__ int cur[256];
  int g = blockIdx.x;
  int j = job_of_bucket(g);
  int b = g - JBBASE[j];
  int relBase = bucketBase[g];
  int st = EBASE[j] + relBase;
  int en = st + bucketTot[g];
  cnt[threadIdx.x] = 0;
  __syncthreads();
  for (int idx = st + threadIdx.x; idx < en; idx += 256)
    atomicAdd(&cnt[scatPairs[idx].x >> 17], 1);
  __syncthreads();
  int v = cnt[threadIdx.x];
  sArr[threadIdx.x] = v;
  __syncthreads();
  for (int d = 1; d < 256; d <<= 1) {
    int t = (threadIdx.x >= d) ? sArr[threadIdx.x - d] : 0;
    __syncthreads();
    sArr[threadIdx.x] += t;
    __syncthreads();
  }
  int excl = sArr[threadIdx.x] - v;
  int node = b * 256 + threadIdx.x;
  if (node < JN[j]) off[NBASE[j] + node] = relBase + excl;
  if (threadIdx.x == 0 && b == JB[j] - 1) off[NBASE[j] + JN[j]] = JE[j];
  cur[threadIdx.x] = st + excl;
  __syncthreads();
  for (int idx = st + threadIdx.x; idx < en; idx += 256) {
    int2 p = scatPairs[idx];
    int dl = p.x >> 17;
    int s = p.x & 0x1FFFF;
    int pos = atomicAdd(&cur[dl], 1);
    csrPairs[pos] = make_int2(s, p.y);
  }
}

// ---------------- props ----------------
__global__ __launch_bounds__(256) void csr_prop128_kernel(
    const int* __restrict__ off, const int2* __restrict__ pairs,
    const float* __restrict__ h, float* __restrict__ y, ushort* __restrict__ ybf,
    const float* __restrict__ prev, float scale, int N) {
  int r = blockIdx.x * 8 + (threadIdx.x >> 5);
  int l = threadIdx.x & 31;
  if (r >= N) return;
  int s = off[r], e = off[r + 1];
  const float4* h4 = (const float4*)h;
  float ax = 0.f, ay = 0.f, az = 0.f, aw = 0.f;
  int j = s;
  for (; j + 4 <= e; j += 4) {
    int2 p0 = pairs[j], p1 = pairs[j + 1], p2 = pairs[j + 2], p3 = pairs[j + 3];
    float4 v0 = h4[(size_t)p0.x * 32 + l];
    float4 v1 = h4[(size_t)p1.x * 32 + l];
    float4 v2 = h4[(size_t)p2.x * 32 + l];
    float4 v3 = h4[(size_t)p3.x * 32 + l];
    float w0 = __int_as_float(p0.y), w1 = __int_as_float(p1.y);
    float w2 = __int_as_float(p2.y), w3 = __int_as_float(p3.y);
    ax += w0 * v0.x + w1 * v1.x + w2 * v2.x + w3 * v3.x;
    ay += w0 * v0.y + w1 * v1.y + w2 * v2.y + w3 * v3.y;
    az += w0 * v0.z + w1 * v1.z + w2 * v2.z + w3 * v3.z;
    aw += w0 * v0.w + w1 * v1.w + w2 * v2.w + w3 * v3.w;
  }
  for (; j < e; ++j) {
    int2 p = pairs[j];
    float4 v0 = h4[(size_t)p.x * 32 + l];
    float w = __int_as_float(p.y);
    ax += w * v0.x; ay += w * v0.y; az += w * v0.z; aw += w * v0.w;
  }
  float4 v = make_float4(scale * ax, scale * ay, scale * az, scale * aw);
  if (prev) {
    float4 pv = ((const float4*)prev)[(size_t)r * 32 + l];
    v.x -= pv.x; v.y -= pv.y; v.z -= pv.z; v.w -= pv.w;
  }
  if (y) ((float4*)y)[(size_t)r * 32 + l] = v;
  uint2 sp = make_uint2(f2bf(v.x) | ((unsigned)f2bf(v.y) << 16),
                        f2bf(v.z) | ((unsigned)f2bf(v.w) << 16));
  ((uint2*)ybf)[(size_t)r * 32 + l] = sp;
}

// level-0: slab float4 per T_k; also writes bf16 A-row shadow slot kout
__global__ void csr_prop3_kernel(const int* __restrict__ off, const int2* __restrict__ pairs,
                                 const float4* __restrict__ h, float4* __restrict__ y,
                                 const float4* __restrict__ prev, float scale, int N,
                                 ushort* __restrict__ ybf, int kout) {
  int r = blockIdx.x * blockDim.x + threadIdx.x;
  if (r >= N) return;
  int s = off[r], e = off[r + 1];
  float ax = 0.f, ay = 0.f, az = 0.f;
  int j = s;
  for (; j + 4 <= e; j += 4) {
    int2 p0 = pairs[j], p1 = pairs[j + 1], p2 = pairs[j + 2], p3 = pairs[j + 3];
    float4 h0 = h[p0.x], h1 = h[p1.x], h2 = h[p2.x], h3 = h[p3.x];
    float w0 = __int_as_float(p0.y), w1 = __int_as_float(p1.y);
    float w2 = __int_as_float(p2.y), w3 = __int_as_float(p3.y);
    ax += w0 * h0.x + w1 * h1.x + w2 * h2.x + w3 * h3.x;
    ay += w0 * h0.y + w1 * h1.y + w2 * h2.y + w3 * h3.y;
    az += w0 * h0.z + w1 * h1.z + w2 * h2.z + w3 * h3.z;
  }
  for (; j < e; ++j) {
    int2 p = pairs[j];
    float4 hv = h[p.x];
    float w = __int_as_float(p.y);
    ax += w * hv.x; ay += w * hv.y; az += w * hv.z;
  }
  float4 v = make_float4(scale * ax, scale * ay, scale * az, 0.f);
  if (prev) {
    float4 pv = prev[r];
    v.x -= pv.x; v.y -= pv.y; v.z -= pv.z;
  }
  y[r] = v;
  uint2 sp = make_uint2(f2bf(v.x) | ((unsigned)f2bf(v.y) << 16), (unsigned)f2bf(v.z));
  *(uint2*)(ybf + (size_t)r * 32 + kout * 4) = sp;
}

// copyx: fp32 slab T0 + zero-init full bf16 A-row with slot 0 = x
__global__ void copyx_kernel(const float* __restrict__ x, float4* __restrict__ Tb,
                             ushort* __restrict__ Abf, int N) {
  int r = blockIdx.x * 256 + threadIdx.x;
  if (r >= N) return;
  float x0 = x[3 * r], x1 = x[3 * r + 1], x2 = x[3 * r + 2];
  Tb[r] = make_float4(x0, x1, x2, 0.f);
  uint4 z = make_uint4(0, 0, 0, 0);
  uint4 first = make_uint4(f2bf(x0) | ((unsigned)f2bf(x1) << 16), (unsigned)f2bf(x2), 0, 0);
  uint4* p = (uint4*)(Abf + (size_t)r * 32);
  p[0] = first; p[1] = z; p[2] = z; p[3] = z;
}

// h0 = relu(b0 + A[M,32]bf16 @ W0b[32,128]) via single-chunk MFMA
__global__ __launch_bounds__(256, 2) void h0_mfma_kernel(
    const ushort* __restrict__ Abf, const ushort* __restrict__ W0b,
    const float* __restrict__ b0, float* __restrict__ h0, int M) {
  __shared__ ushort Al[64][40];
  __shared__ ushort Bl[128][40];
  const int tid = threadIdx.x;
  const int rowBase = blockIdx.x * 64;
  const int wave = tid >> 6;
  const int lane = tid & 63;
  const int m16 = lane & 15;
  const int quad = lane >> 4;
  {
    int sRow = tid >> 2;
    int sK8 = (tid & 3) * 8;
    int row = rowBase + sRow;
    uint4 av = make_uint4(0, 0, 0, 0);
    if (row < M) av = *(const uint4*)(Abf + (size_t)row * 32 + sK8);
    *(uint4*)&Al[sRow][sK8] = av;
  }
#pragma unroll
  for (int l = 0; l < 2; ++l) {
    int lin = tid + l * 256;
    int bRow = lin >> 2;
    int bK8 = (lin & 3) * 8;
    *(uint4*)&Bl[bRow][bK8] = *(const uint4*)(W0b + (size_t)bRow * 32 + bK8);
  }
  __syncthreads();
  short8 a = *(const short8*)&Al[wave * 16 + m16][quad * 8];
  floatx4 acc[8];
#pragma unroll
  for (int c = 0; c < 8; ++c) {
    floatx4 z;
    z[0] = 0.f; z[1] = 0.f; z[2] = 0.f; z[3] = 0.f;
    short8 b = *(const short8*)&Bl[c * 16 + m16][quad * 8];
    acc[c] = __builtin_amdgcn_mfma_f32_16x16x32_bf16(a, b, z, 0, 0, 0);
  }
#pragma unroll
  for (int c = 0; c < 8; ++c) {
    int col = c * 16 + m16;
    float bv = b0[col];
#pragma unroll
    for (int r = 0; r < 4; ++r) {
      int row = rowBase + wave * 16 + quad * 4 + r;
      if (row < M) h0[(size_t)row * 128 + col] = fmaxf(acc[c][r] + bv, 0.f);
    }
  }
}

// ---------------- weight prep (Wt1, Wt2, W0b) ----------------
__global__ void prep_w_kernel(const float* __restrict__ W0, const float* __restrict__ W1,
                              const float* __restrict__ W2, ushort* __restrict__ W0b,
                              ushort* __restrict__ Wt1, ushort* __restrict__ Wt2) {
  int i = blockIdx.x * 256 + threadIdx.x;
  if (i < 768 * 128) {
    int k = i / 128, n = i - k * 128;
    Wt1[(size_t)n * 768 + k] = f2bf(W1[i]);
  } else if (i < 768 * 128 + 768 * 256) {
    int i2 = i - 768 * 128;
    int k = i2 / 256, n = i2 - k * 256;
    Wt2[(size_t)n * 768 + k] = f2bf(W2[i2]);
  } else {
    int i3 = i - 768 * 128 - 768 * 256;
    if (i3 < 128 * 32) {
      int col = i3 >> 5, k = i3 & 31;
      int a = k >> 2, jj = k & 3;
      float v = (k < 24 && jj < 3) ? W0[(a * 3 + jj) * 128 + col] : 0.f;
      W0b[(size_t)col * 32 + k] = f2bf(v);
    }
  }
}

// ---------------- main GEMM (bf16 A, unchanged) ----------------
template <int RELU>
__global__ __launch_bounds__(256, 2) void gemm_mfma_kernel(
    const ushort* __restrict__ Tbf, const ushort* __restrict__ Wt,
    const float* __restrict__ bias, float* __restrict__ C, int M, int N) {
  __shared__ ushort Al[64][40];
  __shared__ ushort Bl[128][40];
  const int tid = threadIdx.x;
  const int rowBase = blockIdx.x * 64;
  const int colBase = blockIdx.y * 128;
  const int wave = tid >> 6;
  const int lane = tid & 63;
  const int m16 = lane & 15;
  const int quad = lane >> 4;
  const size_t Mstride = (size_t)M * 128;

  floatx4 acc[8];
#pragma unroll
  for (int c = 0; c < 8; ++c)
#pragma unroll
    for (int r = 0; r < 4; ++r) acc[c][r] = 0.f;

  const int sRow = tid >> 2;
  const int sK8 = (tid & 3) * 8;
  const int growA = rowBase + sRow;
  const bool aValid = growA < M;

  for (int kc = 0; kc < 24; ++kc) {
    uint4 av = make_uint4(0, 0, 0, 0);
    if (aValid)
      av = *(const uint4*)(Tbf + (size_t)(kc >> 2) * Mstride + (size_t)growA * 128
                           + ((kc & 3) << 5) + sK8);
    *(uint4*)&Al[sRow][sK8] = av;
#pragma unroll
    for (int l = 0; l < 2; ++l) {
      int lin = tid + l * 256;
      int bRow = lin >> 2;
      int bK8 = (lin & 3) * 8;
      *(uint4*)&Bl[bRow][bK8] =
          *(const uint4*)(Wt + (size_t)(colBase + bRow) * 768 + kc * 32 + bK8);
    }
    __syncthreads();

    short8 a = *(const short8*)&Al[wave * 16 + m16][quad * 8];
#pragma unroll
    for (int c = 0; c < 8; ++c) {
      short8 b = *(const short8*)&Bl[c * 16 + m16][quad * 8];
      acc[c] = __builtin_amdgcn_mfma_f32_16x16x32_bf16(a, b, acc[c], 0, 0, 0);
    }
    __syncthreads();
  }

#pragma unroll
  for (int c = 0; c < 8; ++c) {
    int col = colBase + c * 16 + m16;
    float bv = bias[col];
#pragma unroll
    for (int r = 0; r < 4; ++r) {
      int row = rowBase + wave * 16 + quad * 4 + r;
      if (row < M) {
        float v = acc[c][r] + bv;
        if (RELU) v = fmaxf(v, 0.f);
        C[(size_t)row * N + col] = v;
      }
    }
  }
}

// ---------------- linear head ----------------
__global__ void initout_kernel(float* __restrict__ out, const float* __restrict__ linb) {
  int i = threadIdx.x;
  if (i < 10) out[i] = linb[i];
}

__global__ __launch_bounds__(256) void linear_kernel(const float* __restrict__ Wl,
                                                     const float* __restrict__ h,
                                                     float* __restrict__ out, int D) {
  float p[10];
#pragma unroll
  for (int j = 0; j < 10; ++j) p[j] = 0.f;
  int stride = gridDim.x * blockDim.x;
  for (int i = blockIdx.x * blockDim.x + threadIdx.x; i < D; i += stride) {
    float hv = h[i];
#pragma unroll
    for (int j = 0; j < 10; ++j) p[j] += Wl[(size_t)j * D + i] * hv;
  }
#pragma unroll
  for (int j = 0; j < 10; ++j) {
#pragma unroll
    for (int off = 32; off > 0; off >>= 1) p[j] += __shfl_down(p[j], off, 64);
  }
  __shared__ float s[4][10];
  int wave = threadIdx.x >> 6, lane = threadIdx.x & 63;
  if (lane == 0) {
#pragma unroll
    for (int j = 0; j < 10; ++j) s[wave][j] = p[j];
  }
  __syncthreads();
  if (threadIdx.x < 10) {
    float t = s[0][threadIdx.x] + s[1][threadIdx.x] + s[2][threadIdx.x] + s[3][threadIdx.x];
    atomicAdd(&out[threadIdx.x], t);
  }
}

// ---------------- host orchestration ----------------
extern "C" void kernel_launch(void* const* d_in, const int* in_sizes, int n_in,
                              void* d_out, int out_size, void* d_ws, size_t ws_size,
                              hipStream_t stream) {
  const float* x    = (const float*)d_in[0];
  const int*   ei0  = (const int*)d_in[1];
  const int*   ei1  = (const int*)d_in[2];
  const int*   ei2  = (const int*)d_in[3];
  const float* W0   = (const float*)d_in[4];
  const float* b0   = (const float*)d_in[5];
  const float* W1   = (const float*)d_in[6];
  const float* b1   = (const float*)d_in[7];
  const float* W2   = (const float*)d_in[8];
  const float* b2   = (const float*)d_in[9];
  const int*   D0r  = (const int*)d_in[10];
  const int*   D0c  = (const int*)d_in[11];
  const float* D0v  = (const float*)d_in[12];
  const int*   D1r  = (const int*)d_in[13];
  const int*   D1c  = (const int*)d_in[14];
  const float* D1v  = (const float*)d_in[15];
  const float* linW = (const float*)d_in[16];
  const float* linb = (const float*)d_in[17];
  float* out = (float*)d_out;
  (void)in_sizes; (void)n_in; (void)out_size; (void)ws_size;

  const int* src0 = ei0;            const int* dst0 = ei0 + cE0;
  const int* src1 = ei1;            const int* dst1 = ei1 + cE1;
  const int* src2 = ei2;            const int* dst2 = ei2 + cE2;

  float* ws = (float*)d_ws;
  size_t off = 0;
  auto alloc = [&](size_t n) {
    float* p = ws + off;
    off += (n + 63) & ~size_t(63);
    return p;
  };
  float* dinv       = alloc(DEG_TOTAL);
  int*   cntCB      = (int*)alloc((size_t)TCB * BSTRIDE);
  int*   bucketTot  = (int*)alloc(TB);
  int*   bucketBase = (int*)alloc(TB);
  int*   scatSrc    = (int*)alloc(S_TOTAL);
  int2*  scatPairs  = (int2*)alloc((size_t)2 * E_TOTAL);
  int2*  csrPairs   = (int2*)alloc((size_t)2 * E_TOTAL);
  int*   offArr     = (int*)alloc(NPAD_TOTAL);
  ushort* W0b       = (ushort*)alloc(128 * 32 / 2);
  ushort* Wt1       = (ushort*)alloc(768 * 128 / 2);
  ushort* Wt2       = (ushort*)alloc(768 * 256 / 2);
  float4* Tb0       = (float4*)alloc((size_t)6 * cN0 * 4);   // 6 fp32 slabs
  ushort* Abf0      = (ushort*)alloc((size_t)cN0 * 16);      // [N0][32] bf16
  float* h0buf      = alloc((size_t)cN0 * 128);
  float* Tlvl1      = alloc((size_t)6 * cN1 * 128);
  ushort* Tbf1      = (ushort*)alloc((size_t)6 * cN1 * 64);
  float* out1       = alloc((size_t)cN1 * 128);
  float* Tlvl2      = alloc((size_t)6 * cN2 * 128);
  ushort* Tbf2      = (ushort*)alloc((size_t)6 * cN2 * 64);
  float* out2       = alloc((size_t)cN2 * 256);

  auto nb = [](long long n) { return (unsigned)((n + 255) / 256); };

  // ---- atomic-free CSR build ----
  c1_count_kernel<<<TCB, 256, 0, stream>>>(dst0, dst1, dst2, D0r, D1r,
                                           src0, src1, src2, cntCB);
  c2a_scan_kernel<<<TB, 256, 0, stream>>>(cntCB, bucketTot);
  c2b_scan_kernel<<<8, 256, 0, stream>>>(bucketTot, bucketBase);
  c3_src_kernel<<<TCB - JCBASE[5], 256, 0, stream>>>(src0, src1, src2,
                                                     cntCB, bucketBase, scatSrc);
  ddeg_kernel<<<TB - JBBASE[5], 256, 0, stream>>>(scatSrc, bucketTot, bucketBase, dinv);
  c3_dst_kernel<<<JCBASE[5], 256, 0, stream>>>(dst0, src0, dst1, src1, dst2, src2,
                                               D0r, D0c, D0v, D1r, D1c, D1v,
                                               dinv, cntCB, bucketBase, scatPairs);
  dcsr_kernel<<<JBBASE[5], 256, 0, stream>>>(scatPairs, bucketTot, bucketBase,
                                             offArr, csrPairs);
  prep_w_kernel<<<nb(768 * 384 + 128 * 32), 256, 0, stream>>>(W0, W1, W2, W0b, Wt1, Wt2);

  auto seg_off   = [&](int s) { return offArr + NBASE[s]; };
  auto seg_pairs = [&](int s) { return csrPairs + EBASE[s]; };

  // ================= Level 0 (F=3 -> 128) =================
  copyx_kernel<<<nb(cN0), 256, 0, stream>>>(x, Tb0, Abf0, cN0);
  {
    auto Tk = [&](int k) { return Tb0 + (size_t)k * cN0; };
    csr_prop3_kernel<<<nb(cN0), 256, 0, stream>>>(seg_off(0), seg_pairs(0),
        Tk(0), Tk(1), nullptr, 1.f, cN0, Abf0, 1);
    csr_prop3_kernel<<<nb(cN0), 256, 0, stream>>>(seg_off(0), seg_pairs(0),
        Tk(1), Tk(2), Tk(0), 2.f, cN0, Abf0, 2);
    csr_prop3_kernel<<<nb(cN0), 256, 0, stream>>>(seg_off(0), seg_pairs(0),
        Tk(2), Tk(3), Tk(1), 2.f, cN0, Abf0, 3);
    csr_prop3_kernel<<<nb(cN0), 256, 0, stream>>>(seg_off(0), seg_pairs(0),
        Tk(3), Tk(4), Tk(2), 2.f, cN0, Abf0, 4);
    csr_prop3_kernel<<<nb(cN0), 256, 0, stream>>>(seg_off(0), seg_pairs(0),
        Tk(4), Tk(5), Tk(3), 2.f, cN0, Abf0, 5);
  }
  // MFMA h0, then pool0 gather -> Tlvl1 block 0 (fp32 + bf16)
  h0_mfma_kernel<<<(cN0 + 63) / 64, 256, 0, stream>>>(Abf0, W0b, b0, h0buf, cN0);
  csr_prop128_kernel<<<(cN1 + 7) / 8, 256, 0, stream>>>(
      seg_off(3), seg_pairs(3), h0buf, Tlvl1, Tbf1, nullptr, 1.f, cN1);

  // ================= Level 1 =================
  {
    auto Tk  = [&](int k) { return Tlvl1 + (size_t)k * cN1 * 128; };
    auto Tbk = [&](int k) { return Tbf1 + (size_t)k * cN1 * 128; };
    auto prop = [&](int kin, int kout, int kprev, float scale, bool needF32) {
      csr_prop128_kernel<<<(cN1 + 7) / 8, 256, 0, stream>>>(
          seg_off(1), seg_pairs(1), Tk(kin), needF32 ? Tk(kout) : nullptr, Tbk(kout),
          (kprev >= 0) ? Tk(kprev) : nullptr, scale, cN1);
    };
    prop(0, 1, -1, 1.f, true);
    prop(1, 2, 0, 2.f, true);
    prop(2, 3, 1, 2.f, true);
    prop(3, 4, 2, 2.f, true);
    prop(4, 5, 3, 2.f, false);
    dim3 g((cN1 + 63) / 64, 1);
    gemm_mfma_kernel<1><<<g, 256, 0, stream>>>(Tbf1, Wt1, b1, out1, cN1, 128);
  }

  // pool1: out1 -> Tlvl2 block 0
  csr_prop128_kernel<<<(cN2 + 7) / 8, 256, 0, stream>>>(
      seg_off(4), seg_pairs(4), out1, Tlvl2, Tbf2, nullptr, 1.f, cN2);

  // ================= Level 2 (no relu, N=256) =================
  {
    auto Tk  = [&](int k) { return Tlvl2 + (size_t)k * cN2 * 128; };
    auto Tbk = [&](int k) { return Tbf2 + (size_t)k * cN2 * 128; };
    auto prop = [&](int kin, int kout, int kprev, float scale, bool needF32) {
      csr_prop128_kernel<<<(cN2 + 7) / 8, 256, 0, stream>>>(
          seg_off(2), seg_pairs(2), Tk(kin), needF32 ? Tk(kout) : nullptr, Tbk(kout),
          (kprev >= 0) ? Tk(kprev) : nullptr, scale, cN2);
    };
    prop(0, 1, -1, 1.f, true);
    prop(1, 2, 0, 2.f, true);
    prop(2, 3, 1, 2.f, true);
    prop(3, 4, 2, 2.f, true);
    prop(4, 5, 3, 2.f, false);
    dim3 g((cN2 + 63) / 64, 2);
    gemm_mfma_kernel<0><<<g, 256, 0, stream>>>(Tbf2, Wt2, b2, out2, cN2, 256);
  }

  // ---- linear head ----
  initout_kernel<<<1, 64, 0, stream>>>(out, linb);
  linear_kernel<<<512, 256, 0, stream>>>(linW, out2, out, cD);
}